// Round 8
// baseline (434.154 us; speedup 1.0000x reference)
//
#include <hip/hip_runtime.h>
#include <hip/hip_bf16.h>
#include <math.h>

// Problem constants
#define BB 8
#define SS 2048
#define TT (BB * SS)      // 16384 tokens
#define DM 256
#define DI 512
#define DSTATE 16
#define DCONV 4
#define NLAYERS 2
#define VOCAB 256
#define LOG_VOCAB 5.545177444479562f
#define RMS_EPS 1.1920929e-07f
#define LOG2E 1.4426950408889634f
#define LN2 0.6931471805599453f

#define TW 16            // tokens per fused block (R8: halved for 4 blocks/CU)
#define XST 520          // xcs LDS row stride (bf16): 1040B -> only 2-way bank aliasing (free)
#define BMST 20          // Bms LDS row stride (f32)

typedef __attribute__((ext_vector_type(8))) __bf16 bf16x8;
typedef __attribute__((ext_vector_type(4))) __bf16 bf16x4;
typedef __attribute__((ext_vector_type(2))) __bf16 bf16x2;
typedef __attribute__((ext_vector_type(4))) float f32x4;

// ---- fast transcendentals (1-ulp class; entropy margin vs THR=0.5 is ~0.4) ----
__device__ __forceinline__ float fexp(float x) { return __builtin_amdgcn_exp2f(x * LOG2E); }
__device__ __forceinline__ float fexp2(float x) { return __builtin_amdgcn_exp2f(x); }
__device__ __forceinline__ float flog(float x) { return __builtin_amdgcn_logf(x) * LN2; }
__device__ __forceinline__ float frcp(float x) { return __builtin_amdgcn_rcpf(x); }
__device__ __forceinline__ float fsigmoid(float x) { return frcp(1.f + fexp(-x)); }
__device__ __forceinline__ float fsoftplus(float x) {
  return fmaxf(x, 0.f) + flog(1.f + fexp(-fabsf(x)));
}

// ---------------------------------------------------------------------------
// bf16 MFMA GEMM (m97 structure): C[M,N] = A[M,K] @ Bt[N,K]^T  (in_proj only)
// ---------------------------------------------------------------------------
__device__ __forceinline__ void gl2lds16(const void* g, void* l) {
  __builtin_amdgcn_global_load_lds(
      (const __attribute__((address_space(1))) void*)g,
      (__attribute__((address_space(3))) void*)l, 16, 0, 0);
}

__global__ __launch_bounds__(256) void gemm_mfma(
    const __bf16* __restrict__ A,   // [M][K]
    const __bf16* __restrict__ Bt,  // [N][K]  (W^T)
    __hip_bfloat16* __restrict__ C, // [M][N]
    int M, int N, int K) {
  __shared__ __align__(16) __bf16 As[128 * 32];
  __shared__ __align__(16) __bf16 Bs[128 * 32];
  int tid = threadIdx.x;
  int lane = tid & 63;
  int wave = tid >> 6;
  int wm = (wave & 1) * 64;
  int wn = (wave >> 1) * 64;
  int m0 = blockIdx.y * 128;
  int n0 = blockIdx.x * 128;

  int r = tid >> 2;
  int kc = (tid & 3) * 8;
  int fr = lane & 15;
  int fk = (lane >> 4) * 8;

  f32x4 acc[4][4] = {};

  for (int k0 = 0; k0 < K; k0 += 32) {
    gl2lds16(A + (size_t)(m0 + r) * K + k0 + kc, As + r * 32 + kc);
    gl2lds16(A + (size_t)(m0 + 64 + r) * K + k0 + kc, As + (64 + r) * 32 + kc);
    gl2lds16(Bt + (size_t)(n0 + r) * K + k0 + kc, Bs + r * 32 + kc);
    gl2lds16(Bt + (size_t)(n0 + 64 + r) * K + k0 + kc, Bs + (64 + r) * 32 + kc);
    __syncthreads();

    bf16x8 af[4], bfr[4];
#pragma unroll
    for (int i = 0; i < 4; ++i) {
      af[i] = *(const bf16x8*)(As + (wm + i * 16 + fr) * 32 + fk);
      bfr[i] = *(const bf16x8*)(Bs + (wn + i * 16 + fr) * 32 + fk);
    }
#pragma unroll
    for (int i = 0; i < 4; ++i)
#pragma unroll
      for (int j = 0; j < 4; ++j)
        acc[i][j] = __builtin_amdgcn_mfma_f32_16x16x32_bf16(af[i], bfr[j], acc[i][j], 0, 0, 0);
    __syncthreads();
  }

  int cr = (lane >> 4) * 4;
  int cc = lane & 15;
#pragma unroll
  for (int i = 0; i < 4; ++i) {
    int mrow = m0 + wm + i * 16 + cr;
#pragma unroll
    for (int j = 0; j < 4; ++j) {
      int ncol = n0 + wn + j * 16 + cc;
#pragma unroll
      for (int rg = 0; rg < 4; ++rg)
        C[(size_t)(mrow + rg) * N + ncol] = __float2bfloat16(acc[i][j][rg]);
    }
  }
}

// ---------------------------------------------------------------------------
// Merged prep: weight transposes/casts + A2 + embedding gather, ONE dispatch.
// ---------------------------------------------------------------------------
__device__ __forceinline__ void tcast_seg(const float* __restrict__ src,
                                          __hip_bfloat16* __restrict__ dst,
                                          int i, int K, int N) {
  int n = i / K, k = i - n * K;
  dst[i] = __float2bfloat16(src[(size_t)k * N + n]);
}

#define PREP_TOTAL (16384 + 65536 + 2 * (262144 + 262144 + 131072 + 16384))
#define PREP_ALL (PREP_TOTAL + TT * DM)

__global__ void prep_kernel(const float* __restrict__ A_log, float* __restrict__ A2,
                            const float* __restrict__ head_w, __hip_bfloat16* __restrict__ headWt,
                            const float* __restrict__ in_proj_w, __hip_bfloat16* __restrict__ inWt,
                            const float* __restrict__ dt_w, __hip_bfloat16* __restrict__ dtWt,
                            const float* __restrict__ out_w, __hip_bfloat16* __restrict__ oWt,
                            const float* __restrict__ x_proj_w, __hip_bfloat16* __restrict__ xpWt,
                            const int* __restrict__ bytes, const float* __restrict__ embed_w,
                            __hip_bfloat16* __restrict__ xb) {
  int i = blockIdx.x * 256 + threadIdx.x;
  if (i >= PREP_ALL) return;
  if (i >= PREP_TOTAL) {  // embedding gather
    i -= PREP_TOTAL;
    int t = i >> 8, c = i & 255;
    xb[i] = __float2bfloat16(embed_w[(size_t)bytes[t] * DM + c]);
    return;
  }
  if (i < 16384) { A2[i] = -fexp(A_log[i]) * LOG2E; return; }
  i -= 16384;
  if (i < 65536) { tcast_seg(head_w, headWt, i, 256, 256); return; }
  i -= 65536;
  int l = i / 671744;
  i -= l * 671744;
  if (i < 262144) { tcast_seg(in_proj_w + (size_t)l * 262144, inWt + (size_t)l * 262144, i, 256, 1024); return; }
  i -= 262144;
  if (i < 262144) { tcast_seg(dt_w + (size_t)l * 262144, dtWt + (size_t)l * 262144, i, 512, 512); return; }
  i -= 262144;
  if (i < 131072) { tcast_seg(out_w + (size_t)l * 131072, oWt + (size_t)l * 131072, i, 512, 256); return; }
  i -= 131072;
  tcast_seg(x_proj_w + (size_t)l * 16384, xpWt + (size_t)l * 16384, i, 512, 32);
}

// ---------------------------------------------------------------------------
// Fused Mamba layer (post-in_proj), R8 restructure for occupancy:
// 16-token tile, 256 threads (4 waves), grid = TT/16 = 1024 blocks.
// LDS ~22 KB -> 4 blocks/CU with __launch_bounds__(256,4) (VGPR cap 128).
// conv+silu -> bmat (K-split 4 waves + LDS reduce) -> dt-GEMM -> ssm +
// silu(z) fused in-register -> y to LDS -> out-GEMM -> residual+rmsnorm.
// R5-R7 lesson: this kernel is phase-chain latency-bound; 2-3 resident
// blocks couldn't cover ~6 barrier-drained phases. Half tile -> 2x blocks,
// half chain length.
// ---------------------------------------------------------------------------
__global__ __launch_bounds__(256, 4) void mamba_fused(
    const __hip_bfloat16* __restrict__ xz,   // [TT][1024]: x_in | z
    const __bf16* __restrict__ dtW,          // [512][512]  W^T
    const __bf16* __restrict__ oW,           // [256][512]  W^T
    const __bf16* __restrict__ xpW,          // [32][512]   W^T (rows 0..15 = B)
    const float* __restrict__ cw, const float* __restrict__ cb,
    const float* __restrict__ A2, const float* __restrict__ dtb,
    const float* __restrict__ Dp, const float* __restrict__ nw,
    __hip_bfloat16* __restrict__ xb) {
  __shared__ __align__(16) __bf16 xcs[TW * XST];  // 16,640 B
  __shared__ float bpart[4 * 16 * 16];            //  4,096 B
  __shared__ float Bms[TW * BMST];                //  1,280 B
  __shared__ float rmsp[TW * 4];                  //    256 B

  int tid = threadIdx.x;
  int lane = tid & 63;
  int w = tid >> 6;
  int quad = lane >> 4;
  int l15 = lane & 15;
  int t0 = blockIdx.x * TW;
  int s0 = t0 & (SS - 1);

  // ---- P0: causal depthwise conv + bias + silu -> xcs ----
  // thread owns 2 channels x all 16 tokens
  {
    int d0 = tid * 2;
    float w0[4], w1[4];
#pragma unroll
    for (int k = 0; k < 4; ++k) {
      w0[k] = cw[d0 * 4 + k];
      w1[k] = cw[(d0 + 1) * 4 + k];
    }
    float b0 = cb[d0], b1 = cb[d0 + 1];
    float h0x = 0, h0y = 0, h1x = 0, h1y = 0, h2x = 0, h2y = 0;
    if (s0 > 0) {  // halo in-bounds (s0 >= 16 when nonzero)
      bf16x2 p0 = *(const bf16x2*)(xz + (size_t)(t0 - 3) * 1024 + d0);
      bf16x2 p1 = *(const bf16x2*)(xz + (size_t)(t0 - 2) * 1024 + d0);
      bf16x2 p2 = *(const bf16x2*)(xz + (size_t)(t0 - 1) * 1024 + d0);
      h0x = (float)p0[0]; h0y = (float)p0[1];
      h1x = (float)p1[0]; h1y = (float)p1[1];
      h2x = (float)p2[0]; h2y = (float)p2[1];
    }
#pragma unroll 4
    for (int s = 0; s < TW; ++s) {
      bf16x2 cur = *(const bf16x2*)(xz + (size_t)(t0 + s) * 1024 + d0);
      float cx = (float)cur[0], cy = (float)cur[1];
      float a0 = b0 + w0[0] * h0x + w0[1] * h1x + w0[2] * h2x + w0[3] * cx;
      float a1 = b1 + w1[0] * h0y + w1[1] * h1y + w1[2] * h2y + w1[3] * cy;
      bf16x2 o;
      o[0] = (__bf16)(a0 * fsigmoid(a0));
      o[1] = (__bf16)(a1 * fsigmoid(a1));
      *(bf16x2*)(xcs + s * XST + d0) = o;
      h0x = h1x; h1x = h2x; h2x = cx;
      h0y = h1y; h1y = h2y; h2y = cy;
    }
  }
  __syncthreads();

  // ---- P1a: bmat partials, K split across 4 waves ----
  {
    f32x4 bacc = {};
#pragma unroll
    for (int i = 0; i < 4; ++i) {
      int k0 = w * 128 + i * 32;
      bf16x8 a = *(const bf16x8*)(xcs + l15 * XST + k0 + quad * 8);          // token rows
      bf16x8 b = *(const bf16x8*)(xpW + l15 * DI + k0 + quad * 8);           // state rows
      bacc = __builtin_amdgcn_mfma_f32_16x16x32_bf16(a, b, bacc, 0, 0, 0);
    }
#pragma unroll
    for (int rg = 0; rg < 4; ++rg)
      bpart[w * 256 + (quad * 4 + rg) * 16 + l15] = bacc[rg];
  }
  __syncthreads();

  // ---- P1b: reduce 4 K-partials -> Bms (256 threads = 16 tok x 16 states) ----
  {
    int tok = tid >> 4, n = tid & 15;
    Bms[tok * BMST + n] = bpart[0 * 256 + tok * 16 + n] + bpart[1 * 256 + tok * 16 + n] +
                          bpart[2 * 256 + tok * 16 + n] + bpart[3 * 256 + tok * 16 + n];
  }
  __syncthreads();

  // ---- P2: dt-GEMM: wave owns 128 channels ----
  int dbase = w * 128;
  f32x4 acc[8] = {};
#pragma unroll 2
  for (int k0 = 0; k0 < DI; k0 += 32) {
    bf16x8 af = *(const bf16x8*)(xcs + l15 * XST + k0 + quad * 8);
    bf16x8 bfr[8];
#pragma unroll
    for (int ni = 0; ni < 8; ++ni)
      bfr[ni] = *(const bf16x8*)(dtW + (size_t)(dbase + ni * 16 + l15) * DI + k0 + quad * 8);
#pragma unroll
    for (int ni = 0; ni < 8; ++ni)
      acc[ni] = __builtin_amdgcn_mfma_f32_16x16x32_bf16(af, bfr[ni], acc[ni], 0, 0, 0);
  }

  // ---- P2b: ssm + silu(z) in-register: acc (dtlin) -> y*silu(z) ----
#pragma unroll
  for (int ni = 0; ni < 8; ++ni) {
    int d = dbase + ni * 16 + l15;
    float dtbv = dtb[d];
    float dpv = Dp[d];
    const f32x4* ar = (const f32x4*)(A2 + d * DSTATE);
    f32x4 av[4];
#pragma unroll
    for (int q = 0; q < 4; ++q) av[q] = ar[q];
#pragma unroll
    for (int rg = 0; rg < 4; ++rg) {
      int tl = quad * 4 + rg;
      const f32x4* br = (const f32x4*)(Bms + tl * BMST);
      float dt = fsoftplus(acc[ni][rg] + dtbv);
      float s = 0.f;
#pragma unroll
      for (int q = 0; q < 4; ++q) {
        f32x4 bq = br[q];
#pragma unroll
        for (int j = 0; j < 4; ++j) s += fexp2(av[q][j] * dt) * bq[j];
      }
      float xcv = (float)xcs[tl * XST + d];
      float y = dt * xcv * s + dpv * xcv;
      float z = (float)xz[(size_t)(t0 + tl) * 1024 + DI + d];
      acc[ni][rg] = y * z * fsigmoid(z);
    }
  }
  __syncthreads();  // all xcs (xc) reads done block-wide

  // ---- P3: write y' (bf16) into xcs (overwrite) ----
#pragma unroll
  for (int ni = 0; ni < 8; ++ni)
#pragma unroll
    for (int rg = 0; rg < 4; ++rg) {
      int tl = quad * 4 + rg;
      xcs[tl * XST + dbase + ni * 16 + l15] = (__bf16)acc[ni][rg];
    }
  __syncthreads();

  // ---- P5: out-GEMM: yout = y' @ oW^T, wave owns 64 cols ----
  int wn = w * 64;
  f32x4 oacc[4] = {};
#pragma unroll 2
  for (int k0 = 0; k0 < DI; k0 += 32) {
    bf16x8 af = *(const bf16x8*)(xcs + l15 * XST + k0 + quad * 8);
    bf16x8 bfr[4];
#pragma unroll
    for (int ni = 0; ni < 4; ++ni)
      bfr[ni] = *(const bf16x8*)(oW + (size_t)(wn + ni * 16 + l15) * DI + k0 + quad * 8);
#pragma unroll
    for (int ni = 0; ni < 4; ++ni)
      oacc[ni] = __builtin_amdgcn_mfma_f32_16x16x32_bf16(af, bfr[ni], oacc[ni], 0, 0, 0);
  }

  // ---- P6: v = yout + xb; rmsnorm; write xb ----
#pragma unroll
  for (int rg = 0; rg < 4; ++rg) {
    int tl = quad * 4 + rg;
    int t = t0 + tl;
    float sq = 0.f;
#pragma unroll
    for (int ni = 0; ni < 4; ++ni) {
      int c = wn + ni * 16 + l15;
      float v = oacc[ni][rg] + (float)xb[(size_t)t * DM + c];
      oacc[ni][rg] = v;
      sq += v * v;
    }
    sq += __shfl_xor(sq, 1);
    sq += __shfl_xor(sq, 2);
    sq += __shfl_xor(sq, 4);
    sq += __shfl_xor(sq, 8);
    if (l15 == 0) rmsp[tl * 4 + w] = sq;
  }
  __syncthreads();
#pragma unroll
  for (int rg = 0; rg < 4; ++rg) {
    int tl = quad * 4 + rg;
    int t = t0 + tl;
    float tot = rmsp[tl * 4 + 0] + rmsp[tl * 4 + 1] + rmsp[tl * 4 + 2] + rmsp[tl * 4 + 3];
    float r = rsqrtf(tot * (1.f / DM) + RMS_EPS);
#pragma unroll
    for (int ni = 0; ni < 4; ++ni) {
      int c = wn + ni * 16 + l15;
      xb[(size_t)t * DM + c] = __float2bfloat16(oacc[ni][rg] * r * nw[c]);
    }
  }
}

// ---------------------------------------------------------------------------
// head-GEMM + entropy fused: wave owns 16 full rows (256 cols) -> in-wave
// entropy reduce. grid = TT/64, block 256. Shift-invariant H = ln S - U/S
// (logits bounded ~|l|<5, no max subtraction needed).
// ---------------------------------------------------------------------------
#define HST 264
__global__ __launch_bounds__(256) void head_entropy(
    const __hip_bfloat16* __restrict__ xb, const __bf16* __restrict__ hW,
    float* __restrict__ ent) {
  __shared__ __align__(16) __bf16 as[64 * HST];
  int tid = threadIdx.x;
  int lane = tid & 63;
  int w = tid >> 6;
  int quad = lane >> 4;
  int l15 = lane & 15;
  int t0 = blockIdx.x * 64;
  for (int i = tid; i < 64 * 32; i += 256) {
    int r = i >> 5, c8 = (i & 31) * 8;
    *(bf16x8*)(as + r * HST + c8) = *(const bf16x8*)(xb + (size_t)(t0 + r) * DM + c8);
  }
  __syncthreads();
  f32x4 acc[16] = {};
  int mrow = w * 16 + l15;
#pragma unroll
  for (int k0 = 0; k0 < DM; k0 += 32) {
    bf16x8 a = *(const bf16x8*)(as + mrow * HST + k0 + quad * 8);
#pragma unroll
    for (int ni = 0; ni < 16; ++ni) {
      bf16x8 b = *(const bf16x8*)(hW + (size_t)(ni * 16 + l15) * DM + k0 + quad * 8);
      acc[ni] = __builtin_amdgcn_mfma_f32_16x16x32_bf16(a, b, acc[ni], 0, 0, 0);
    }
  }
#pragma unroll
  for (int rg = 0; rg < 4; ++rg) {
    float s = 0.f, u = 0.f;
#pragma unroll
    for (int ni = 0; ni < 16; ++ni) {
      float l = acc[ni][rg];
      float e = fexp(l);
      s += e;
      u += e * l;
    }
    s += __shfl_xor(s, 1); u += __shfl_xor(u, 1);
    s += __shfl_xor(s, 2); u += __shfl_xor(u, 2);
    s += __shfl_xor(s, 4); u += __shfl_xor(u, 4);
    s += __shfl_xor(s, 8); u += __shfl_xor(u, 8);
    if (l15 == 0) {
      int t = t0 + w * 16 + quad * 4 + rg;
      ent[t] = (flog(s) - u * frcp(s)) * (1.f / LOG_VOCAB);
    }
  }
}

// boundary scan + byte_to_patch + patch starts. 1 block, 8 waves (1 per batch).
__global__ void scan_kernel(const float* __restrict__ ent, float* __restrict__ btp_out,
                            int* __restrict__ pstart, int* __restrict__ npatch) {
  __shared__ unsigned long long masks[BB][32];
  __shared__ int wpre[BB][33];
  int tid = threadIdx.x;
  int w = tid >> 6, lane = tid & 63;
  int b = w;
  int size = 1;
  for (int w64 = 0; w64 < 32; ++w64) {
    int s = w64 * 64 + lane;
    float e = ent[b * SS + s];
    unsigned long long cb = __ballot(e > 0.5f);
    if (lane == 0) {
      unsigned long long bits;
      if (w64 == 0) {
        bits = 1ull;
        for (int j = 1; j < 64; ++j) {
          int c = (int)((cb >> j) & 1ull);
          int nb = c | (size >= 8);
          size = nb ? 1 : size + 1;
          bits |= ((unsigned long long)nb) << j;
        }
      } else if (cb == ~0ull) {
        bits = cb;
        size = 1;
      } else {
        bits = 0ull;
        for (int j = 0; j < 64; ++j) {
          int c = (int)((cb >> j) & 1ull);
          int nb = c | (size >= 8);
          size = nb ? 1 : size + 1;
          bits |= ((unsigned long long)nb) << j;
        }
      }
      masks[w][w64] = bits;
    }
  }
  __syncthreads();
  if (lane == 0) {
    int acc = 0;
    for (int i = 0; i < 32; ++i) {
      wpre[w][i] = acc;
      acc += __popcll(masks[w][i]);
    }
    wpre[w][32] = acc;
    npatch[b] = acc;
  }
  __syncthreads();
  for (int w64 = 0; w64 < 32; ++w64) {
    int s = w64 * 64 + lane;
    unsigned long long word = masks[w][w64];
    unsigned long long below =
        word & ((lane == 63) ? ~0ull : ((1ull << (lane + 1)) - 1ull));
    int btp = wpre[w][w64] + __popcll(below) - 1;
    btp_out[b * SS + s] = (float)btp;
    if ((word >> lane) & 1ull) pstart[b * SS + btp] = s;
  }
}

// per-patch mean pooling (contiguous ranges), zero-fill padding patches
__global__ void patch_kernel(const float* __restrict__ bemb, const int* __restrict__ pstart,
                             const int* __restrict__ npatch, float* __restrict__ pe_out,
                             float* __restrict__ plen_out) {
  int bp = blockIdx.x;
  int b = bp >> 11;
  int p = bp & (SS - 1);
  int c = threadIdx.x;
  int np = npatch[b];
  size_t outidx = (size_t)bp * DM + c;
  if (p >= np) {
    pe_out[outidx] = 0.f;
    if (c == 0) plen_out[bp] = 0.f;
    return;
  }
  int start = pstart[b * SS + p];
  int end = (p + 1 < np) ? pstart[b * SS + p + 1] : SS;
  float acc = 0.f;
  for (int t = start; t < end; ++t) acc += bemb[((size_t)b * SS + t) * DM + c];
  pe_out[outidx] = acc * frcp((float)(end - start));
  if (c == 0) plen_out[bp] = (float)(end - start);
}

// ---------------------------------------------------------------------------
// Launcher — 8 dispatches total
// ---------------------------------------------------------------------------
extern "C" void kernel_launch(void* const* d_in, const int* in_sizes, int n_in,
                              void* d_out, int out_size, void* d_ws, size_t ws_size,
                              hipStream_t stream) {
  const int* bytes = (const int*)d_in[0];
  const float* bemb = (const float*)d_in[1];
  const float* embed_w = (const float*)d_in[2];
  const float* in_proj_w = (const float*)d_in[3];
  const float* conv_w = (const float*)d_in[4];
  const float* conv_b = (const float*)d_in[5];
  const float* x_proj_w = (const float*)d_in[6];
  const float* dt_w = (const float*)d_in[7];
  const float* dt_b = (const float*)d_in[8];
  const float* A_log = (const float*)d_in[9];
  const float* D_param = (const float*)d_in[10];
  const float* out_w = (const float*)d_in[11];
  const float* norm_w = (const float*)d_in[12];
  const float* head_w = (const float*)d_in[13];

  float* out = (float*)d_out;
  float* pe_out = out;                      // (B,S,DM)
  float* plen_out = out + (size_t)TT * DM;  // (B,S)
  float* btp_out = plen_out + TT;           // (B,S)

  char* wsb = (char*)d_ws;
  size_t off = 0;
  auto alloc = [&](size_t bytes_) -> void* {
    void* p = wsb + off;
    off += (bytes_ + 255) & ~(size_t)255;
    return p;
  };
  float* A2 = (float*)alloc((size_t)NLAYERS * DI * DSTATE * 4);
  __hip_bfloat16* xb = (__hip_bfloat16*)alloc((size_t)TT * DM * 2);
  __hip_bfloat16* xz = (__hip_bfloat16*)alloc((size_t)TT * 2 * DI * 2);
  float* ent = (float*)alloc((size_t)TT * 4);
  int* pstart = (int*)alloc((size_t)TT * 4);
  int* npatch = (int*)alloc(256);
  __hip_bfloat16* inWt = (__hip_bfloat16*)alloc((size_t)NLAYERS * 2 * DI * DM * 2);
  __hip_bfloat16* dtWt = (__hip_bfloat16*)alloc((size_t)NLAYERS * DI * DI * 2);
  __hip_bfloat16* oWt = (__hip_bfloat16*)alloc((size_t)NLAYERS * DM * DI * 2);
  __hip_bfloat16* xpWt = (__hip_bfloat16*)alloc((size_t)NLAYERS * 32 * DI * 2);
  __hip_bfloat16* headWt = (__hip_bfloat16*)alloc((size_t)VOCAB * DM * 2);

  // 1: weight prep + embedding
  prep_kernel<<<(PREP_ALL + 255) / 256, 256, 0, stream>>>(
      A_log, A2, head_w, headWt, in_proj_w, inWt, dt_w, dtWt, out_w, oWt,
      x_proj_w, xpWt, bytes, embed_w, xb);

  // 2..5: two Mamba layers, 2 dispatches each
  for (int l = 0; l < NLAYERS; ++l) {
    gemm_mfma<<<dim3(2 * DI / 128, TT / 128), 256, 0, stream>>>(
        (const __bf16*)xb, (const __bf16*)(inWt + (size_t)l * 2 * DI * DM),
        (__hip_bfloat16*)xz, TT, 2 * DI, DM);
    mamba_fused<<<TT / TW, 256, 0, stream>>>(
        xz, (const __bf16*)(dtWt + (size_t)l * DI * DI),
        (const __bf16*)(oWt + (size_t)l * DM * DI),
        (const __bf16*)(xpWt + (size_t)l * 32 * DI),
        conv_w + (size_t)l * DI * DCONV, conv_b + (size_t)l * DI,
        A2 + (size_t)l * DI * DSTATE, dt_b + (size_t)l * DI,
        D_param + (size_t)l * DI, norm_w + (size_t)l * DM, xb);
  }

  // 6: head + entropy
  head_entropy<<<TT / 64, 256, 0, stream>>>(xb, (const __bf16*)headWt, ent);

  // 7: boundary scan
  scan_kernel<<<1, 512, 0, stream>>>(ent, btp_out, pstart, npatch);

  // 8: patch mean pooling
  patch_kernel<<<TT, DM, 0, stream>>>(bemb, pstart, npatch, pe_out, plen_out);
}

// Round 9
// 408.531 us; speedup vs baseline: 1.0627x; 1.0627x over previous
//
#include <hip/hip_runtime.h>
#include <hip/hip_bf16.h>
#include <math.h>

// Problem constants
#define BB 8
#define SS 2048
#define TT (BB * SS)      // 16384 tokens
#define DM 256
#define DI 512
#define DSTATE 16
#define DCONV 4
#define NLAYERS 2
#define VOCAB 256
#define LOG_VOCAB 5.545177444479562f
#define RMS_EPS 1.1920929e-07f
#define LOG2E 1.4426950408889634f
#define LN2 0.6931471805599453f

#define TW 32            // tokens per fused block
#define XST 520          // xcs LDS row stride (bf16): 1040B -> only 2-way bank aliasing (free)
#define BMST 20          // Bms LDS row stride (f32)

typedef __attribute__((ext_vector_type(8))) __bf16 bf16x8;
typedef __attribute__((ext_vector_type(4))) __bf16 bf16x4;
typedef __attribute__((ext_vector_type(2))) __bf16 bf16x2;
typedef __attribute__((ext_vector_type(4))) float f32x4;

// ---- fast transcendentals (1-ulp class; entropy margin vs THR=0.5 is ~0.4) ----
__device__ __forceinline__ float fexp(float x) { return __builtin_amdgcn_exp2f(x * LOG2E); }
__device__ __forceinline__ float fexp2(float x) { return __builtin_amdgcn_exp2f(x); }
__device__ __forceinline__ float flog(float x) { return __builtin_amdgcn_logf(x) * LN2; }
__device__ __forceinline__ float frcp(float x) { return __builtin_amdgcn_rcpf(x); }
__device__ __forceinline__ float fsigmoid(float x) { return frcp(1.f + fexp(-x)); }
__device__ __forceinline__ float fsoftplus(float x) {
  return fmaxf(x, 0.f) + flog(1.f + fexp(-fabsf(x)));
}

// ---------------------------------------------------------------------------
// bf16 MFMA GEMM (m97 structure): C[M,N] = A[M,K] @ Bt[N,K]^T  (in_proj only)
// ---------------------------------------------------------------------------
__device__ __forceinline__ void gl2lds16(const void* g, void* l) {
  __builtin_amdgcn_global_load_lds(
      (const __attribute__((address_space(1))) void*)g,
      (__attribute__((address_space(3))) void*)l, 16, 0, 0);
}

__global__ __launch_bounds__(256) void gemm_mfma(
    const __bf16* __restrict__ A,   // [M][K]
    const __bf16* __restrict__ Bt,  // [N][K]  (W^T)
    __hip_bfloat16* __restrict__ C, // [M][N]
    int M, int N, int K) {
  __shared__ __align__(16) __bf16 As[128 * 32];
  __shared__ __align__(16) __bf16 Bs[128 * 32];
  int tid = threadIdx.x;
  int lane = tid & 63;
  int wave = tid >> 6;
  int wm = (wave & 1) * 64;
  int wn = (wave >> 1) * 64;
  int m0 = blockIdx.y * 128;
  int n0 = blockIdx.x * 128;

  int r = tid >> 2;
  int kc = (tid & 3) * 8;
  int fr = lane & 15;
  int fk = (lane >> 4) * 8;

  f32x4 acc[4][4] = {};

  for (int k0 = 0; k0 < K; k0 += 32) {
    gl2lds16(A + (size_t)(m0 + r) * K + k0 + kc, As + r * 32 + kc);
    gl2lds16(A + (size_t)(m0 + 64 + r) * K + k0 + kc, As + (64 + r) * 32 + kc);
    gl2lds16(Bt + (size_t)(n0 + r) * K + k0 + kc, Bs + r * 32 + kc);
    gl2lds16(Bt + (size_t)(n0 + 64 + r) * K + k0 + kc, Bs + (64 + r) * 32 + kc);
    __syncthreads();

    bf16x8 af[4], bfr[4];
#pragma unroll
    for (int i = 0; i < 4; ++i) {
      af[i] = *(const bf16x8*)(As + (wm + i * 16 + fr) * 32 + fk);
      bfr[i] = *(const bf16x8*)(Bs + (wn + i * 16 + fr) * 32 + fk);
    }
#pragma unroll
    for (int i = 0; i < 4; ++i)
#pragma unroll
      for (int j = 0; j < 4; ++j)
        acc[i][j] = __builtin_amdgcn_mfma_f32_16x16x32_bf16(af[i], bfr[j], acc[i][j], 0, 0, 0);
    __syncthreads();
  }

  int cr = (lane >> 4) * 4;
  int cc = lane & 15;
#pragma unroll
  for (int i = 0; i < 4; ++i) {
    int mrow = m0 + wm + i * 16 + cr;
#pragma unroll
    for (int j = 0; j < 4; ++j) {
      int ncol = n0 + wn + j * 16 + cc;
#pragma unroll
      for (int rg = 0; rg < 4; ++rg)
        C[(size_t)(mrow + rg) * N + ncol] = __float2bfloat16(acc[i][j][rg]);
    }
  }
}

// ---------------------------------------------------------------------------
// Merged prep: weight transposes/casts + A2 + embedding gather, ONE dispatch.
// ---------------------------------------------------------------------------
__device__ __forceinline__ void tcast_seg(const float* __restrict__ src,
                                          __hip_bfloat16* __restrict__ dst,
                                          int i, int K, int N) {
  int n = i / K, k = i - n * K;
  dst[i] = __float2bfloat16(src[(size_t)k * N + n]);
}

#define PREP_TOTAL (16384 + 65536 + 2 * (262144 + 262144 + 131072 + 16384))
#define PREP_ALL (PREP_TOTAL + TT * DM)

__global__ void prep_kernel(const float* __restrict__ A_log, float* __restrict__ A2,
                            const float* __restrict__ head_w, __hip_bfloat16* __restrict__ headWt,
                            const float* __restrict__ in_proj_w, __hip_bfloat16* __restrict__ inWt,
                            const float* __restrict__ dt_w, __hip_bfloat16* __restrict__ dtWt,
                            const float* __restrict__ out_w, __hip_bfloat16* __restrict__ oWt,
                            const float* __restrict__ x_proj_w, __hip_bfloat16* __restrict__ xpWt,
                            const int* __restrict__ bytes, const float* __restrict__ embed_w,
                            __hip_bfloat16* __restrict__ xb) {
  int i = blockIdx.x * 256 + threadIdx.x;
  if (i >= PREP_ALL) return;
  if (i >= PREP_TOTAL) {  // embedding gather
    i -= PREP_TOTAL;
    int t = i >> 8, c = i & 255;
    xb[i] = __float2bfloat16(embed_w[(size_t)bytes[t] * DM + c]);
    return;
  }
  if (i < 16384) { A2[i] = -fexp(A_log[i]) * LOG2E; return; }
  i -= 16384;
  if (i < 65536) { tcast_seg(head_w, headWt, i, 256, 256); return; }
  i -= 65536;
  int l = i / 671744;
  i -= l * 671744;
  if (i < 262144) { tcast_seg(in_proj_w + (size_t)l * 262144, inWt + (size_t)l * 262144, i, 256, 1024); return; }
  i -= 262144;
  if (i < 262144) { tcast_seg(dt_w + (size_t)l * 262144, dtWt + (size_t)l * 262144, i, 512, 512); return; }
  i -= 262144;
  if (i < 131072) { tcast_seg(out_w + (size_t)l * 131072, oWt + (size_t)l * 131072, i, 512, 256); return; }
  i -= 131072;
  tcast_seg(x_proj_w + (size_t)l * 16384, xpWt + (size_t)l * 16384, i, 512, 32);
}

// ---------------------------------------------------------------------------
// Fused Mamba layer (post-in_proj), R9: TW=32 + 4 waves = R5-class per-wave
// ILP (acc[2][8], 16 MFMA/K-iter) with 2x R5's block count (grid 512).
// NO min-waves bound: R6/R8 proved min-waves>=4 forces the 64-VGPR cliff and
// ~30-60 MB/dispatch scratch spill. Compiler free -> ~160-200 VGPR, no spill,
// 2 blocks/CU by LDS (44.5 KB).
// bf16-only residual stream (xb); fp32 x eliminated (saves 48 MB/layer HBM).
// ---------------------------------------------------------------------------
__global__ __launch_bounds__(256) void mamba_fused(
    const __hip_bfloat16* __restrict__ xz,   // [TT][1024]: x_in | z
    const __bf16* __restrict__ dtW,          // [512][512]  W^T
    const __bf16* __restrict__ oW,           // [256][512]  W^T
    const __bf16* __restrict__ xpW,          // [32][512]   W^T (rows 0..15 = B)
    const float* __restrict__ cw, const float* __restrict__ cb,
    const float* __restrict__ A2, const float* __restrict__ dtb,
    const float* __restrict__ Dp, const float* __restrict__ nw,
    __hip_bfloat16* __restrict__ xb) {
  __shared__ __align__(16) __bf16 xcs[TW * XST];  // 33,280 B
  __shared__ float bpart[4 * TW * 16];            //  8,192 B
  __shared__ float Bms[TW * BMST];                //  2,560 B
  __shared__ float rmsp[TW * 4];                  //    512 B

  int tid = threadIdx.x;
  int lane = tid & 63;
  int w = tid >> 6;
  int quad = lane >> 4;
  int l15 = lane & 15;
  int t0 = blockIdx.x * TW;
  int s0 = t0 & (SS - 1);

  // ---- P0: causal depthwise conv + bias + silu -> xcs ----
  // thread owns 2 channels x all 32 tokens
  {
    int d0 = tid * 2;
    float w0[4], w1[4];
#pragma unroll
    for (int k = 0; k < 4; ++k) {
      w0[k] = cw[d0 * 4 + k];
      w1[k] = cw[(d0 + 1) * 4 + k];
    }
    float b0 = cb[d0], b1 = cb[d0 + 1];
    float h0x = 0, h0y = 0, h1x = 0, h1y = 0, h2x = 0, h2y = 0;
    if (s0 > 0) {  // halo in-bounds (s0 >= 32 when nonzero)
      bf16x2 p0 = *(const bf16x2*)(xz + (size_t)(t0 - 3) * 1024 + d0);
      bf16x2 p1 = *(const bf16x2*)(xz + (size_t)(t0 - 2) * 1024 + d0);
      bf16x2 p2 = *(const bf16x2*)(xz + (size_t)(t0 - 1) * 1024 + d0);
      h0x = (float)p0[0]; h0y = (float)p0[1];
      h1x = (float)p1[0]; h1y = (float)p1[1];
      h2x = (float)p2[0]; h2y = (float)p2[1];
    }
#pragma unroll 4
    for (int s = 0; s < TW; ++s) {
      bf16x2 cur = *(const bf16x2*)(xz + (size_t)(t0 + s) * 1024 + d0);
      float cx = (float)cur[0], cy = (float)cur[1];
      float a0 = b0 + w0[0] * h0x + w0[1] * h1x + w0[2] * h2x + w0[3] * cx;
      float a1 = b1 + w1[0] * h0y + w1[1] * h1y + w1[2] * h2y + w1[3] * cy;
      bf16x2 o;
      o[0] = (__bf16)(a0 * fsigmoid(a0));
      o[1] = (__bf16)(a1 * fsigmoid(a1));
      *(bf16x2*)(xcs + s * XST + d0) = o;
      h0x = h1x; h1x = h2x; h2x = cx;
      h0y = h1y; h1y = h2y; h2y = cy;
    }
  }
  __syncthreads();

  // ---- P1a: bmat partials, K split across 4 waves, 2 m-frags (32 tokens) ----
  {
    f32x4 bacc[2] = {};
#pragma unroll
    for (int i = 0; i < 4; ++i) {
      int k0 = w * 128 + i * 32;
      bf16x8 a0 = *(const bf16x8*)(xcs + l15 * XST + k0 + quad * 8);
      bf16x8 a1 = *(const bf16x8*)(xcs + (16 + l15) * XST + k0 + quad * 8);
      bf16x8 b = *(const bf16x8*)(xpW + l15 * DI + k0 + quad * 8);
      bacc[0] = __builtin_amdgcn_mfma_f32_16x16x32_bf16(a0, b, bacc[0], 0, 0, 0);
      bacc[1] = __builtin_amdgcn_mfma_f32_16x16x32_bf16(a1, b, bacc[1], 0, 0, 0);
    }
#pragma unroll
    for (int mi = 0; mi < 2; ++mi)
#pragma unroll
      for (int rg = 0; rg < 4; ++rg)
        bpart[w * (TW * 16) + (mi * 16 + quad * 4 + rg) * 16 + l15] = bacc[mi][rg];
  }
  __syncthreads();

  // ---- P1b: reduce 4 K-partials -> Bms (512 entries, 256 threads x 2) ----
  for (int e = tid; e < TW * 16; e += 256) {
    int tok = e >> 4, n = e & 15;
    Bms[tok * BMST + n] = bpart[0 * (TW * 16) + tok * 16 + n] +
                          bpart[1 * (TW * 16) + tok * 16 + n] +
                          bpart[2 * (TW * 16) + tok * 16 + n] +
                          bpart[3 * (TW * 16) + tok * 16 + n];
  }
  __syncthreads();

  // ---- P2: dt-GEMM: wave owns 128 channels, 16 MFMA/K-iter ----
  int dbase = w * 128;
  f32x4 acc[2][8] = {};
#pragma unroll
  for (int k0 = 0; k0 < DI; k0 += 32) {
    bf16x8 af[2], bfr[8];
#pragma unroll
    for (int mi = 0; mi < 2; ++mi)
      af[mi] = *(const bf16x8*)(xcs + (mi * 16 + l15) * XST + k0 + quad * 8);
#pragma unroll
    for (int ni = 0; ni < 8; ++ni)
      bfr[ni] = *(const bf16x8*)(dtW + (size_t)(dbase + ni * 16 + l15) * DI + k0 + quad * 8);
#pragma unroll
    for (int mi = 0; mi < 2; ++mi)
#pragma unroll
      for (int ni = 0; ni < 8; ++ni)
        acc[mi][ni] = __builtin_amdgcn_mfma_f32_16x16x32_bf16(af[mi], bfr[ni], acc[mi][ni], 0, 0, 0);
  }

  // ---- P2b: ssm in-register: acc (dtlin) -> y ----
#pragma unroll
  for (int ni = 0; ni < 8; ++ni) {
    int d = dbase + ni * 16 + l15;
    float dtbv = dtb[d];
    float dpv = Dp[d];
    const f32x4* ar = (const f32x4*)(A2 + d * DSTATE);
    f32x4 av[4];
#pragma unroll
    for (int q = 0; q < 4; ++q) av[q] = ar[q];
#pragma unroll
    for (int mi = 0; mi < 2; ++mi) {
#pragma unroll
      for (int rg = 0; rg < 4; ++rg) {
        int tl = mi * 16 + quad * 4 + rg;
        const f32x4* br = (const f32x4*)(Bms + tl * BMST);
        float dt = fsoftplus(acc[mi][ni][rg] + dtbv);
        float s = 0.f;
#pragma unroll
        for (int q = 0; q < 4; ++q) {
          f32x4 bq = br[q];
#pragma unroll
          for (int j = 0; j < 4; ++j) s += fexp2(av[q][j] * dt) * bq[j];
        }
        float xcv = (float)xcs[tl * XST + d];
        acc[mi][ni][rg] = dt * xcv * s + dpv * xcv;
      }
    }
  }
  __syncthreads();  // all xcs (xc) reads done block-wide

  // ---- P3: write y (bf16) into xcs (overwrite) ----
#pragma unroll
  for (int mi = 0; mi < 2; ++mi)
#pragma unroll
    for (int ni = 0; ni < 8; ++ni)
#pragma unroll
      for (int rg = 0; rg < 4; ++rg) {
        int tl = mi * 16 + quad * 4 + rg;
        xcs[tl * XST + dbase + ni * 16 + l15] = (__bf16)acc[mi][ni][rg];
      }
  __syncthreads();

  // ---- P4: y *= silu(z)  (coalesced z reads) ----
  {
    int d0 = tid * 2;
#pragma unroll 4
    for (int s = 0; s < TW; ++s) {
      bf16x2 yv = *(bf16x2*)(xcs + s * XST + d0);
      bf16x2 zv = *(const bf16x2*)(xz + (size_t)(t0 + s) * 1024 + DI + d0);
      float z0 = (float)zv[0], z1 = (float)zv[1];
      bf16x2 o;
      o[0] = (__bf16)((float)yv[0] * z0 * fsigmoid(z0));
      o[1] = (__bf16)((float)yv[1] * z1 * fsigmoid(z1));
      *(bf16x2*)(xcs + s * XST + d0) = o;
    }
  }
  __syncthreads();

  // ---- P5: out-GEMM: yout = y' @ oW^T, wave owns 64 cols ----
  int wn = w * 64;
  f32x4 oacc[2][4] = {};
#pragma unroll
  for (int k0 = 0; k0 < DI; k0 += 32) {
    bf16x8 af[2], bfr[4];
#pragma unroll
    for (int mi = 0; mi < 2; ++mi)
      af[mi] = *(const bf16x8*)(xcs + (mi * 16 + l15) * XST + k0 + quad * 8);
#pragma unroll
    for (int ni = 0; ni < 4; ++ni)
      bfr[ni] = *(const bf16x8*)(oW + (size_t)(wn + ni * 16 + l15) * DI + k0 + quad * 8);
#pragma unroll
    for (int mi = 0; mi < 2; ++mi)
#pragma unroll
      for (int ni = 0; ni < 4; ++ni)
        oacc[mi][ni] = __builtin_amdgcn_mfma_f32_16x16x32_bf16(af[mi], bfr[ni], oacc[mi][ni], 0, 0, 0);
  }

  // ---- P6: v = yout + xb; rmsnorm; write xb ----
#pragma unroll
  for (int mi = 0; mi < 2; ++mi) {
#pragma unroll
    for (int rg = 0; rg < 4; ++rg) {
      int tl = mi * 16 + quad * 4 + rg;
      int t = t0 + tl;
      float sq = 0.f;
#pragma unroll
      for (int ni = 0; ni < 4; ++ni) {
        int c = wn + ni * 16 + l15;
        float v = oacc[mi][ni][rg] + (float)xb[(size_t)t * DM + c];
        oacc[mi][ni][rg] = v;
        sq += v * v;
      }
      sq += __shfl_xor(sq, 1);
      sq += __shfl_xor(sq, 2);
      sq += __shfl_xor(sq, 4);
      sq += __shfl_xor(sq, 8);
      if (l15 == 0) rmsp[tl * 4 + w] = sq;
    }
  }
  __syncthreads();
#pragma unroll
  for (int mi = 0; mi < 2; ++mi) {
#pragma unroll
    for (int rg = 0; rg < 4; ++rg) {
      int tl = mi * 16 + quad * 4 + rg;
      int t = t0 + tl;
      float tot = rmsp[tl * 4 + 0] + rmsp[tl * 4 + 1] + rmsp[tl * 4 + 2] + rmsp[tl * 4 + 3];
      float r = rsqrtf(tot * (1.f / DM) + RMS_EPS);
#pragma unroll
      for (int ni = 0; ni < 4; ++ni) {
        int c = wn + ni * 16 + l15;
        xb[(size_t)t * DM + c] = __float2bfloat16(oacc[mi][ni][rg] * r * nw[c]);
      }
    }
  }
}

// ---------------------------------------------------------------------------
// head-GEMM + entropy fused: wave owns 16 full rows (256 cols) -> in-wave
// entropy reduce. grid = TT/64, block 256. Shift-invariant H = ln S - U/S
// (logits bounded ~|l|<5, no max subtraction needed).
// ---------------------------------------------------------------------------
#define HST 264
__global__ __launch_bounds__(256) void head_entropy(
    const __hip_bfloat16* __restrict__ xb, const __bf16* __restrict__ hW,
    float* __restrict__ ent) {
  __shared__ __align__(16) __bf16 as[64 * HST];
  int tid = threadIdx.x;
  int lane = tid & 63;
  int w = tid >> 6;
  int quad = lane >> 4;
  int l15 = lane & 15;
  int t0 = blockIdx.x * 64;
  for (int i = tid; i < 64 * 32; i += 256) {
    int r = i >> 5, c8 = (i & 31) * 8;
    *(bf16x8*)(as + r * HST + c8) = *(const bf16x8*)(xb + (size_t)(t0 + r) * DM + c8);
  }
  __syncthreads();
  f32x4 acc[16] = {};
  int mrow = w * 16 + l15;
#pragma unroll
  for (int k0 = 0; k0 < DM; k0 += 32) {
    bf16x8 a = *(const bf16x8*)(as + mrow * HST + k0 + quad * 8);
#pragma unroll
    for (int ni = 0; ni < 16; ++ni) {
      bf16x8 b = *(const bf16x8*)(hW + (size_t)(ni * 16 + l15) * DM + k0 + quad * 8);
      acc[ni] = __builtin_amdgcn_mfma_f32_16x16x32_bf16(a, b, acc[ni], 0, 0, 0);
    }
  }
#pragma unroll
  for (int rg = 0; rg < 4; ++rg) {
    float s = 0.f, u = 0.f;
#pragma unroll
    for (int ni = 0; ni < 16; ++ni) {
      float l = acc[ni][rg];
      float e = fexp(l);
      s += e;
      u += e * l;
    }
    s += __shfl_xor(s, 1); u += __shfl_xor(u, 1);
    s += __shfl_xor(s, 2); u += __shfl_xor(u, 2);
    s += __shfl_xor(s, 4); u += __shfl_xor(u, 4);
    s += __shfl_xor(s, 8); u += __shfl_xor(u, 8);
    if (l15 == 0) {
      int t = t0 + w * 16 + quad * 4 + rg;
      ent[t] = (flog(s) - u * frcp(s)) * (1.f / LOG_VOCAB);
    }
  }
}

// boundary scan + byte_to_patch + patch starts. 1 block, 8 waves (1 per batch).
__global__ void scan_kernel(const float* __restrict__ ent, float* __restrict__ btp_out,
                            int* __restrict__ pstart, int* __restrict__ npatch) {
  __shared__ unsigned long long masks[BB][32];
  __shared__ int wpre[BB][33];
  int tid = threadIdx.x;
  int w = tid >> 6, lane = tid & 63;
  int b = w;
  int size = 1;
  for (int w64 = 0; w64 < 32; ++w64) {
    int s = w64 * 64 + lane;
    float e = ent[b * SS + s];
    unsigned long long cb = __ballot(e > 0.5f);
    if (lane == 0) {
      unsigned long long bits;
      if (w64 == 0) {
        bits = 1ull;
        for (int j = 1; j < 64; ++j) {
          int c = (int)((cb >> j) & 1ull);
          int nb = c | (size >= 8);
          size = nb ? 1 : size + 1;
          bits |= ((unsigned long long)nb) << j;
        }
      } else if (cb == ~0ull) {
        bits = cb;
        size = 1;
      } else {
        bits = 0ull;
        for (int j = 0; j < 64; ++j) {
          int c = (int)((cb >> j) & 1ull);
          int nb = c | (size >= 8);
          size = nb ? 1 : size + 1;
          bits |= ((unsigned long long)nb) << j;
        }
      }
      masks[w][w64] = bits;
    }
  }
  __syncthreads();
  if (lane == 0) {
    int acc = 0;
    for (int i = 0; i < 32; ++i) {
      wpre[w][i] = acc;
      acc += __popcll(masks[w][i]);
    }
    wpre[w][32] = acc;
    npatch[b] = acc;
  }
  __syncthreads();
  for (int w64 = 0; w64 < 32; ++w64) {
    int s = w64 * 64 + lane;
    unsigned long long word = masks[w][w64];
    unsigned long long below =
        word & ((lane == 63) ? ~0ull : ((1ull << (lane + 1)) - 1ull));
    int btp = wpre[w][w64] + __popcll(below) - 1;
    btp_out[b * SS + s] = (float)btp;
    if ((word >> lane) & 1ull) pstart[b * SS + btp] = s;
  }
}

// per-patch mean pooling (contiguous ranges), zero-fill padding patches
__global__ void patch_kernel(const float* __restrict__ bemb, const int* __restrict__ pstart,
                             const int* __restrict__ npatch, float* __restrict__ pe_out,
                             float* __restrict__ plen_out) {
  int bp = blockIdx.x;
  int b = bp >> 11;
  int p = bp & (SS - 1);
  int c = threadIdx.x;
  int np = npatch[b];
  size_t outidx = (size_t)bp * DM + c;
  if (p >= np) {
    pe_out[outidx] = 0.f;
    if (c == 0) plen_out[bp] = 0.f;
    return;
  }
  int start = pstart[b * SS + p];
  int end = (p + 1 < np) ? pstart[b * SS + p + 1] : SS;
  float acc = 0.f;
  for (int t = start; t < end; ++t) acc += bemb[((size_t)b * SS + t) * DM + c];
  pe_out[outidx] = acc * frcp((float)(end - start));
  if (c == 0) plen_out[bp] = (float)(end - start);
}

// ---------------------------------------------------------------------------
// Launcher — 8 dispatches total
// ---------------------------------------------------------------------------
extern "C" void kernel_launch(void* const* d_in, const int* in_sizes, int n_in,
                              void* d_out, int out_size, void* d_ws, size_t ws_size,
                              hipStream_t stream) {
  const int* bytes = (const int*)d_in[0];
  const float* bemb = (const float*)d_in[1];
  const float* embed_w = (const float*)d_in[2];
  const float* in_proj_w = (const float*)d_in[3];
  const float* conv_w = (const float*)d_in[4];
  const float* conv_b = (const float*)d_in[5];
  const float* x_proj_w = (const float*)d_in[6];
  const float* dt_w = (const float*)d_in[7];
  const float* dt_b = (const float*)d_in[8];
  const float* A_log = (const float*)d_in[9];
  const float* D_param = (const float*)d_in[10];
  const float* out_w = (const float*)d_in[11];
  const float* norm_w = (const float*)d_in[12];
  const float* head_w = (const float*)d_in[13];

  float* out = (float*)d_out;
  float* pe_out = out;                      // (B,S,DM)
  float* plen_out = out + (size_t)TT * DM;  // (B,S)
  float* btp_out = plen_out + TT;           // (B,S)

  char* wsb = (char*)d_ws;
  size_t off = 0;
  auto alloc = [&](size_t bytes_) -> void* {
    void* p = wsb + off;
    off += (bytes_ + 255) & ~(size_t)255;
    return p;
  };
  float* A2 = (float*)alloc((size_t)NLAYERS * DI * DSTATE * 4);
  __hip_bfloat16* xb = (__hip_bfloat16*)alloc((size_t)TT * DM * 2);
  __hip_bfloat16* xz = (__hip_bfloat16*)alloc((size_t)TT * 2 * DI * 2);
  float* ent = (float*)alloc((size_t)TT * 4);
  int* pstart = (int*)alloc((size_t)TT * 4);
  int* npatch = (int*)alloc(256);
  __hip_bfloat16* inWt = (__hip_bfloat16*)alloc((size_t)NLAYERS * 2 * DI * DM * 2);
  __hip_bfloat16* dtWt = (__hip_bfloat16*)alloc((size_t)NLAYERS * DI * DI * 2);
  __hip_bfloat16* oWt = (__hip_bfloat16*)alloc((size_t)NLAYERS * DM * DI * 2);
  __hip_bfloat16* xpWt = (__hip_bfloat16*)alloc((size_t)NLAYERS * 32 * DI * 2);
  __hip_bfloat16* headWt = (__hip_bfloat16*)alloc((size_t)VOCAB * DM * 2);

  // 1: weight prep + embedding
  prep_kernel<<<(PREP_ALL + 255) / 256, 256, 0, stream>>>(
      A_log, A2, head_w, headWt, in_proj_w, inWt, dt_w, dtWt, out_w, oWt,
      x_proj_w, xpWt, bytes, embed_w, xb);

  // 2..5: two Mamba layers, 2 dispatches each
  for (int l = 0; l < NLAYERS; ++l) {
    gemm_mfma<<<dim3(2 * DI / 128, TT / 128), 256, 0, stream>>>(
        (const __bf16*)xb, (const __bf16*)(inWt + (size_t)l * 2 * DI * DM),
        (__hip_bfloat16*)xz, TT, 2 * DI, DM);
    mamba_fused<<<TT / TW, 256, 0, stream>>>(
        xz, (const __bf16*)(dtWt + (size_t)l * DI * DI),
        (const __bf16*)(oWt + (size_t)l * DM * DI),
        (const __bf16*)(xpWt + (size_t)l * 32 * DI),
        conv_w + (size_t)l * DI * DCONV, conv_b + (size_t)l * DI,
        A2 + (size_t)l * DI * DSTATE, dt_b + (size_t)l * DI,
        D_param + (size_t)l * DI, norm_w + (size_t)l * DM, xb);
  }

  // 6: head + entropy
  head_entropy<<<TT / 64, 256, 0, stream>>>(xb, (const __bf16*)headWt, ent);

  // 7: boundary scan
  scan_kernel<<<1, 512, 0, stream>>>(ent, btp_out, pstart, npatch);

  // 8: patch mean pooling
  patch_kernel<<<TT, DM, 0, stream>>>(bemb, pstart, npatch, pe_out, plen_out);
}

// Round 10
// 366.654 us; speedup vs baseline: 1.1841x; 1.1142x over previous
//
#include <hip/hip_runtime.h>
#include <hip/hip_bf16.h>
#include <math.h>

// Problem constants
#define BB 8
#define SS 2048
#define TT (BB * SS)      // 16384 tokens
#define DM 256
#define DI 512
#define DSTATE 16
#define DCONV 4
#define NLAYERS 2
#define VOCAB 256
#define LOG_VOCAB 5.545177444479562f
#define RMS_EPS 1.1920929e-07f
#define LOG2E 1.4426950408889634f
#define LN2 0.6931471805599453f

#define TW 64            // tokens per fused block (R5 winner config)
#define XST 520          // xcs LDS row stride (bf16): 1040B -> only 2-way bank aliasing (free)
#define BMST 20          // Bms LDS row stride (f32)

typedef __attribute__((ext_vector_type(8))) __bf16 bf16x8;
typedef __attribute__((ext_vector_type(4))) __bf16 bf16x4;
typedef __attribute__((ext_vector_type(2))) __bf16 bf16x2;
typedef __attribute__((ext_vector_type(4))) float f32x4;

// ---- fast transcendentals (1-ulp class; entropy margin vs THR=0.5 is ~0.4) ----
__device__ __forceinline__ float fexp(float x) { return __builtin_amdgcn_exp2f(x * LOG2E); }
__device__ __forceinline__ float fexp2(float x) { return __builtin_amdgcn_exp2f(x); }
__device__ __forceinline__ float flog(float x) { return __builtin_amdgcn_logf(x) * LN2; }
__device__ __forceinline__ float frcp(float x) { return __builtin_amdgcn_rcpf(x); }
__device__ __forceinline__ float fsigmoid(float x) { return frcp(1.f + fexp(-x)); }
__device__ __forceinline__ float fsoftplus(float x) {
  return fmaxf(x, 0.f) + flog(1.f + fexp(-fabsf(x)));
}

// ---------------------------------------------------------------------------
// bf16 MFMA GEMM (m97 structure): C[M,N] = A[M,K] @ Bt[N,K]^T  (in_proj only)
// ---------------------------------------------------------------------------
__device__ __forceinline__ void gl2lds16(const void* g, void* l) {
  __builtin_amdgcn_global_load_lds(
      (const __attribute__((address_space(1))) void*)g,
      (__attribute__((address_space(3))) void*)l, 16, 0, 0);
}

__global__ __launch_bounds__(256) void gemm_mfma(
    const __bf16* __restrict__ A,   // [M][K]
    const __bf16* __restrict__ Bt,  // [N][K]  (W^T)
    __hip_bfloat16* __restrict__ C, // [M][N]
    int M, int N, int K) {
  __shared__ __align__(16) __bf16 As[128 * 32];
  __shared__ __align__(16) __bf16 Bs[128 * 32];
  int tid = threadIdx.x;
  int lane = tid & 63;
  int wave = tid >> 6;
  int wm = (wave & 1) * 64;
  int wn = (wave >> 1) * 64;
  int m0 = blockIdx.y * 128;
  int n0 = blockIdx.x * 128;

  int r = tid >> 2;
  int kc = (tid & 3) * 8;
  int fr = lane & 15;
  int fk = (lane >> 4) * 8;

  f32x4 acc[4][4] = {};

  for (int k0 = 0; k0 < K; k0 += 32) {
    gl2lds16(A + (size_t)(m0 + r) * K + k0 + kc, As + r * 32 + kc);
    gl2lds16(A + (size_t)(m0 + 64 + r) * K + k0 + kc, As + (64 + r) * 32 + kc);
    gl2lds16(Bt + (size_t)(n0 + r) * K + k0 + kc, Bs + r * 32 + kc);
    gl2lds16(Bt + (size_t)(n0 + 64 + r) * K + k0 + kc, Bs + (64 + r) * 32 + kc);
    __syncthreads();

    bf16x8 af[4], bfr[4];
#pragma unroll
    for (int i = 0; i < 4; ++i) {
      af[i] = *(const bf16x8*)(As + (wm + i * 16 + fr) * 32 + fk);
      bfr[i] = *(const bf16x8*)(Bs + (wn + i * 16 + fr) * 32 + fk);
    }
#pragma unroll
    for (int i = 0; i < 4; ++i)
#pragma unroll
      for (int j = 0; j < 4; ++j)
        acc[i][j] = __builtin_amdgcn_mfma_f32_16x16x32_bf16(af[i], bfr[j], acc[i][j], 0, 0, 0);
    __syncthreads();
  }

  int cr = (lane >> 4) * 4;
  int cc = lane & 15;
#pragma unroll
  for (int i = 0; i < 4; ++i) {
    int mrow = m0 + wm + i * 16 + cr;
#pragma unroll
    for (int j = 0; j < 4; ++j) {
      int ncol = n0 + wn + j * 16 + cc;
#pragma unroll
      for (int rg = 0; rg < 4; ++rg)
        C[(size_t)(mrow + rg) * N + ncol] = __float2bfloat16(acc[i][j][rg]);
    }
  }
}

// ---------------------------------------------------------------------------
// R10 prep: tiled LDS transpose (coalesced both sides) + A2 + embedding,
// ONE dispatch. R9's prep did dst-contiguous indexing -> stride-K fp32
// reads, fully uncoalesced (~50 us hidden). 32x32 tiles, +1 pad.
// ---------------------------------------------------------------------------
#define T_HEAD 64
#define T_IN 256
#define T_DT 256
#define T_OUT 128
#define T_XP 16
#define T_LAYER (T_IN + T_DT + T_OUT + T_XP)   // 656
#define T_W (T_HEAD + 2 * T_LAYER)             // 1376
#define T_A2 16
#define T_EMB (TT * DM / 1024)                 // 4096
#define T_ALL (T_W + T_A2 + T_EMB)             // 5488

__global__ __launch_bounds__(256) void prep_kernel(
    const float* __restrict__ A_log, float* __restrict__ A2,
    const float* __restrict__ head_w, __hip_bfloat16* __restrict__ headWt,
    const float* __restrict__ in_proj_w, __hip_bfloat16* __restrict__ inWt,
    const float* __restrict__ dt_w, __hip_bfloat16* __restrict__ dtWt,
    const float* __restrict__ out_w, __hip_bfloat16* __restrict__ oWt,
    const float* __restrict__ x_proj_w, __hip_bfloat16* __restrict__ xpWt,
    const int* __restrict__ bytes, const float* __restrict__ embed_w,
    __hip_bfloat16* __restrict__ xb) {
  int bid = blockIdx.x;
  int tid = threadIdx.x;
  if (bid < T_W) {  // transpose role: dst[n*K+k] = bf16(src[k*N+n])
    const float* src;
    __hip_bfloat16* dst;
    int K, N, t;
    if (bid < T_HEAD) {
      src = head_w; dst = headWt; K = 256; N = 256; t = bid;
    } else {
      int r = bid - T_HEAD;
      int l = r / T_LAYER;
      r -= l * T_LAYER;
      if (r < T_IN) {
        src = in_proj_w + (size_t)l * 262144; dst = inWt + (size_t)l * 262144;
        K = 256; N = 1024; t = r;
      } else if (r < T_IN + T_DT) {
        src = dt_w + (size_t)l * 262144; dst = dtWt + (size_t)l * 262144;
        K = 512; N = 512; t = r - T_IN;
      } else if (r < T_IN + T_DT + T_OUT) {
        src = out_w + (size_t)l * 131072; dst = oWt + (size_t)l * 131072;
        K = 512; N = 256; t = r - T_IN - T_DT;
      } else {
        src = x_proj_w + (size_t)l * 16384; dst = xpWt + (size_t)l * 16384;
        K = 512; N = 32; t = r - T_IN - T_DT - T_OUT;
      }
    }
    int tilesX = N >> 5;
    int kt = t / tilesX, nt = t - kt * tilesX;
    int k0 = kt * 32, n0 = nt * 32;
    __shared__ float tile[32][33];
    int rr = tid >> 3;
    int c4 = (tid & 7) * 4;
    float4 v = *(const float4*)(src + (size_t)(k0 + rr) * N + n0 + c4);
    tile[rr][c4 + 0] = v.x;
    tile[rr][c4 + 1] = v.y;
    tile[rr][c4 + 2] = v.z;
    tile[rr][c4 + 3] = v.w;
    __syncthreads();
    int c = tid >> 3;
    int r4 = (tid & 7) * 4;
    bf16x4 o;
#pragma unroll
    for (int i = 0; i < 4; ++i) o[i] = (__bf16)tile[r4 + i][c];
    *(bf16x4*)(dst + (size_t)(n0 + c) * K + k0 + r4) = o;
  } else if (bid < T_W + T_A2) {  // A2 = -exp(A_log)*log2e
    int i = (bid - T_W) * 1024 + tid * 4;
    float4 v = *(const float4*)(A_log + i);
    f32x4 o;
    o[0] = -fexp(v.x) * LOG2E;
    o[1] = -fexp(v.y) * LOG2E;
    o[2] = -fexp(v.z) * LOG2E;
    o[3] = -fexp(v.w) * LOG2E;
    *(f32x4*)(A2 + i) = o;
  } else {  // embedding gather, 4 tokens per block
    int e = bid - T_W - T_A2;
    int tok = e * 4 + (tid >> 6);
    int col = (tid & 63) * 4;
    float4 v = *(const float4*)(embed_w + (size_t)bytes[tok] * DM + col);
    bf16x4 o;
    o[0] = (__bf16)v.x; o[1] = (__bf16)v.y; o[2] = (__bf16)v.z; o[3] = (__bf16)v.w;
    *(bf16x4*)(xb + (size_t)tok * DM + col) = o;
  }
}

// ---------------------------------------------------------------------------
// Fused Mamba layer (post-in_proj) — R5 winner config (84.9 us measured):
// 64-token tile, 256 threads (4 waves), grid = TT/64 = 256 blocks, 1/CU,
// no min-waves bound (R6/R8: min-waves>=4 forces 64-VGPR cliff + spill).
// bf16-only residual stream (xb). Static LDS 72,704 B.
// ---------------------------------------------------------------------------
__global__ __launch_bounds__(256) void mamba_fused(
    const __hip_bfloat16* __restrict__ xz,   // [TT][1024]: x_in | z
    const __bf16* __restrict__ dtW,          // [512][512]  W^T
    const __bf16* __restrict__ oW,           // [256][512]  W^T
    const __bf16* __restrict__ xpW,          // [32][512]   W^T (rows 0..15 = B)
    const float* __restrict__ cw, const float* __restrict__ cb,
    const float* __restrict__ A2, const float* __restrict__ dtb,
    const float* __restrict__ Dp, const float* __restrict__ nw,
    __hip_bfloat16* __restrict__ xb) {
  __shared__ __align__(16) __bf16 xcs[TW * XST];  // 66,560 B
  __shared__ float Bms[TW * BMST];                //  5,120 B
  __shared__ float rmsp[TW * 4];                  //  1,024 B

  int tid = threadIdx.x;
  int lane = tid & 63;
  int w = tid >> 6;
  int quad = lane >> 4;
  int l15 = lane & 15;
  int t0 = blockIdx.x * TW;
  int s0 = t0 & (SS - 1);

  // ---- P0: causal depthwise conv + bias + silu -> xcs ----
  {
    int d0 = tid * 2;
    float w0[4], w1[4];
#pragma unroll
    for (int k = 0; k < 4; ++k) {
      w0[k] = cw[d0 * 4 + k];
      w1[k] = cw[(d0 + 1) * 4 + k];
    }
    float b0 = cb[d0], b1 = cb[d0 + 1];
    float h0x = 0, h0y = 0, h1x = 0, h1y = 0, h2x = 0, h2y = 0;
    if (s0 > 0) {
      bf16x2 p0 = *(const bf16x2*)(xz + (size_t)(t0 - 3) * 1024 + d0);
      bf16x2 p1 = *(const bf16x2*)(xz + (size_t)(t0 - 2) * 1024 + d0);
      bf16x2 p2 = *(const bf16x2*)(xz + (size_t)(t0 - 1) * 1024 + d0);
      h0x = (float)p0[0]; h0y = (float)p0[1];
      h1x = (float)p1[0]; h1y = (float)p1[1];
      h2x = (float)p2[0]; h2y = (float)p2[1];
    }
#pragma unroll 4
    for (int s = 0; s < TW; ++s) {
      bf16x2 cur = *(const bf16x2*)(xz + (size_t)(t0 + s) * 1024 + d0);
      float cx = (float)cur[0], cy = (float)cur[1];
      float a0 = b0 + w0[0] * h0x + w0[1] * h1x + w0[2] * h2x + w0[3] * cx;
      float a1 = b1 + w1[0] * h0y + w1[1] * h1y + w1[2] * h2y + w1[3] * cy;
      bf16x2 o;
      o[0] = (__bf16)(a0 * fsigmoid(a0));
      o[1] = (__bf16)(a1 * fsigmoid(a1));
      *(bf16x2*)(xcs + s * XST + d0) = o;
      h0x = h1x; h1x = h2x; h2x = cx;
      h0y = h1y; h1y = h2y; h2y = cy;
    }
  }
  __syncthreads();

  // ---- P1: Bmat = xc @ xpW^T (wave w -> tokens w*16..+15) -> Bms ----
  {
    f32x4 bacc = {};
#pragma unroll
    for (int k0 = 0; k0 < DI; k0 += 32) {
      bf16x8 a = *(const bf16x8*)(xcs + (w * 16 + l15) * XST + k0 + quad * 8);
      bf16x8 b = *(const bf16x8*)(xpW + l15 * DI + k0 + quad * 8);
      bacc = __builtin_amdgcn_mfma_f32_16x16x32_bf16(a, b, bacc, 0, 0, 0);
    }
#pragma unroll
    for (int rg = 0; rg < 4; ++rg)
      Bms[(w * 16 + quad * 4 + rg) * BMST + l15] = bacc[rg];
  }
  __syncthreads();

  // ---- P2: dt-GEMM: dtlin = xc @ dtW^T, wave owns channels [w*128, +128) ----
  int dbase = w * 128;
  f32x4 acc[4][8] = {};
#pragma unroll
  for (int k0 = 0; k0 < DI; k0 += 32) {
    bf16x8 af[4], bfr[8];
#pragma unroll
    for (int mi = 0; mi < 4; ++mi)
      af[mi] = *(const bf16x8*)(xcs + (mi * 16 + l15) * XST + k0 + quad * 8);
#pragma unroll
    for (int ni = 0; ni < 8; ++ni)
      bfr[ni] = *(const bf16x8*)(dtW + (size_t)(dbase + ni * 16 + l15) * DI + k0 + quad * 8);
#pragma unroll
    for (int mi = 0; mi < 4; ++mi)
#pragma unroll
      for (int ni = 0; ni < 8; ++ni)
        acc[mi][ni] = __builtin_amdgcn_mfma_f32_16x16x32_bf16(af[mi], bfr[ni], acc[mi][ni], 0, 0, 0);
  }

  // ---- P2b: ssm in-register: acc (dtlin) -> y ----
#pragma unroll
  for (int ni = 0; ni < 8; ++ni) {
    int d = dbase + ni * 16 + l15;
    float dtbv = dtb[d];
    float dpv = Dp[d];
    const f32x4* ar = (const f32x4*)(A2 + d * DSTATE);
    f32x4 av[4];
#pragma unroll
    for (int q = 0; q < 4; ++q) av[q] = ar[q];
#pragma unroll
    for (int mi = 0; mi < 4; ++mi) {
#pragma unroll
      for (int rg = 0; rg < 4; ++rg) {
        int tl = mi * 16 + quad * 4 + rg;
        const f32x4* br = (const f32x4*)(Bms + tl * BMST);
        float dt = fsoftplus(acc[mi][ni][rg] + dtbv);
        float s = 0.f;
#pragma unroll
        for (int q = 0; q < 4; ++q) {
          f32x4 bq = br[q];
#pragma unroll
          for (int j = 0; j < 4; ++j) s += fexp2(av[q][j] * dt) * bq[j];
        }
        float xcv = (float)xcs[tl * XST + d];
        acc[mi][ni][rg] = dt * xcv * s + dpv * xcv;
      }
    }
  }
  __syncthreads();  // all xcs reads done block-wide

  // ---- P3: write y (bf16) into xcs (overwrite) ----
#pragma unroll
  for (int mi = 0; mi < 4; ++mi)
#pragma unroll
    for (int ni = 0; ni < 8; ++ni)
#pragma unroll
      for (int rg = 0; rg < 4; ++rg) {
        int tl = mi * 16 + quad * 4 + rg;
        xcs[tl * XST + dbase + ni * 16 + l15] = (__bf16)acc[mi][ni][rg];
      }
  __syncthreads();

  // ---- P4: y *= silu(z)  (coalesced z reads from global) ----
  {
    int d0 = tid * 2;
#pragma unroll 4
    for (int s = 0; s < TW; ++s) {
      bf16x2 yv = *(bf16x2*)(xcs + s * XST + d0);
      bf16x2 zv = *(const bf16x2*)(xz + (size_t)(t0 + s) * 1024 + DI + d0);
      float z0 = (float)zv[0], z1 = (float)zv[1];
      bf16x2 o;
      o[0] = (__bf16)((float)yv[0] * z0 * fsigmoid(z0));
      o[1] = (__bf16)((float)yv[1] * z1 * fsigmoid(z1));
      *(bf16x2*)(xcs + s * XST + d0) = o;
    }
  }
  __syncthreads();

  // ---- P5: out-GEMM: yout = y' @ oW^T, wave owns cols [w*64, +64) ----
  int wn = w * 64;
  f32x4 oacc[4][4] = {};
#pragma unroll
  for (int k0 = 0; k0 < DI; k0 += 32) {
    bf16x8 af[4], bfr[4];
#pragma unroll
    for (int mi = 0; mi < 4; ++mi)
      af[mi] = *(const bf16x8*)(xcs + (mi * 16 + l15) * XST + k0 + quad * 8);
#pragma unroll
    for (int ni = 0; ni < 4; ++ni)
      bfr[ni] = *(const bf16x8*)(oW + (size_t)(wn + ni * 16 + l15) * DI + k0 + quad * 8);
#pragma unroll
    for (int mi = 0; mi < 4; ++mi)
#pragma unroll
      for (int ni = 0; ni < 4; ++ni)
        oacc[mi][ni] = __builtin_amdgcn_mfma_f32_16x16x32_bf16(af[mi], bfr[ni], oacc[mi][ni], 0, 0, 0);
  }

  // ---- P6: v = yout + xb; rmsnorm; write xb ----
#pragma unroll
  for (int mi = 0; mi < 4; ++mi) {
#pragma unroll
    for (int rg = 0; rg < 4; ++rg) {
      int tl = mi * 16 + quad * 4 + rg;
      int t = t0 + tl;
      float sq = 0.f;
#pragma unroll
      for (int ni = 0; ni < 4; ++ni) {
        int c = wn + ni * 16 + l15;
        float v = oacc[mi][ni][rg] + (float)xb[(size_t)t * DM + c];
        oacc[mi][ni][rg] = v;
        sq += v * v;
      }
      sq += __shfl_xor(sq, 1);
      sq += __shfl_xor(sq, 2);
      sq += __shfl_xor(sq, 4);
      sq += __shfl_xor(sq, 8);
      if (l15 == 0) rmsp[tl * 4 + w] = sq;
    }
  }
  __syncthreads();
#pragma unroll
  for (int mi = 0; mi < 4; ++mi) {
#pragma unroll
    for (int rg = 0; rg < 4; ++rg) {
      int tl = mi * 16 + quad * 4 + rg;
      int t = t0 + tl;
      float tot = rmsp[tl * 4 + 0] + rmsp[tl * 4 + 1] + rmsp[tl * 4 + 2] + rmsp[tl * 4 + 3];
      float r = rsqrtf(tot * (1.f / DM) + RMS_EPS);
#pragma unroll
      for (int ni = 0; ni < 4; ++ni) {
        int c = wn + ni * 16 + l15;
        xb[(size_t)t * DM + c] = __float2bfloat16(oacc[mi][ni][rg] * r * nw[c]);
      }
    }
  }
}

// ---------------------------------------------------------------------------
// head-GEMM + entropy fused: wave owns 16 full rows (256 cols) -> in-wave
// entropy reduce. grid = TT/64, block 256. Shift-invariant H = ln S - U/S
// (logits bounded ~|l|<5, no max subtraction needed).
// ---------------------------------------------------------------------------
#define HST 264
__global__ __launch_bounds__(256) void head_entropy(
    const __hip_bfloat16* __restrict__ xb, const __bf16* __restrict__ hW,
    float* __restrict__ ent) {
  __shared__ __align__(16) __bf16 as[64 * HST];
  int tid = threadIdx.x;
  int lane = tid & 63;
  int w = tid >> 6;
  int quad = lane >> 4;
  int l15 = lane & 15;
  int t0 = blockIdx.x * 64;
  for (int i = tid; i < 64 * 32; i += 256) {
    int r = i >> 5, c8 = (i & 31) * 8;
    *(bf16x8*)(as + r * HST + c8) = *(const bf16x8*)(xb + (size_t)(t0 + r) * DM + c8);
  }
  __syncthreads();
  f32x4 acc[16] = {};
  int mrow = w * 16 + l15;
#pragma unroll
  for (int k0 = 0; k0 < DM; k0 += 32) {
    bf16x8 a = *(const bf16x8*)(as + mrow * HST + k0 + quad * 8);
#pragma unroll
    for (int ni = 0; ni < 16; ++ni) {
      bf16x8 b = *(const bf16x8*)(hW + (size_t)(ni * 16 + l15) * DM + k0 + quad * 8);
      acc[ni] = __builtin_amdgcn_mfma_f32_16x16x32_bf16(a, b, acc[ni], 0, 0, 0);
    }
  }
#pragma unroll
  for (int rg = 0; rg < 4; ++rg) {
    float s = 0.f, u = 0.f;
#pragma unroll
    for (int ni = 0; ni < 16; ++ni) {
      float l = acc[ni][rg];
      float e = fexp(l);
      s += e;
      u += e * l;
    }
    s += __shfl_xor(s, 1); u += __shfl_xor(u, 1);
    s += __shfl_xor(s, 2); u += __shfl_xor(u, 2);
    s += __shfl_xor(s, 4); u += __shfl_xor(u, 4);
    s += __shfl_xor(s, 8); u += __shfl_xor(u, 8);
    if (l15 == 0) {
      int t = t0 + w * 16 + quad * 4 + rg;
      ent[t] = (flog(s) - u * frcp(s)) * (1.f / LOG_VOCAB);
    }
  }
}

// boundary scan + byte_to_patch + patch starts. 1 block, 8 waves (1 per batch).
__global__ void scan_kernel(const float* __restrict__ ent, float* __restrict__ btp_out,
                            int* __restrict__ pstart, int* __restrict__ npatch) {
  __shared__ unsigned long long masks[BB][32];
  __shared__ int wpre[BB][33];
  int tid = threadIdx.x;
  int w = tid >> 6, lane = tid & 63;
  int b = w;
  int size = 1;
  for (int w64 = 0; w64 < 32; ++w64) {
    int s = w64 * 64 + lane;
    float e = ent[b * SS + s];
    unsigned long long cb = __ballot(e > 0.5f);
    if (lane == 0) {
      unsigned long long bits;
      if (w64 == 0) {
        bits = 1ull;
        for (int j = 1; j < 64; ++j) {
          int c = (int)((cb >> j) & 1ull);
          int nb = c | (size >= 8);
          size = nb ? 1 : size + 1;
          bits |= ((unsigned long long)nb) << j;
        }
      } else if (cb == ~0ull) {
        bits = cb;
        size = 1;
      } else {
        bits = 0ull;
        for (int j = 0; j < 64; ++j) {
          int c = (int)((cb >> j) & 1ull);
          int nb = c | (size >= 8);
          size = nb ? 1 : size + 1;
          bits |= ((unsigned long long)nb) << j;
        }
      }
      masks[w][w64] = bits;
    }
  }
  __syncthreads();
  if (lane == 0) {
    int acc = 0;
    for (int i = 0; i < 32; ++i) {
      wpre[w][i] = acc;
      acc += __popcll(masks[w][i]);
    }
    wpre[w][32] = acc;
    npatch[b] = acc;
  }
  __syncthreads();
  for (int w64 = 0; w64 < 32; ++w64) {
    int s = w64 * 64 + lane;
    unsigned long long word = masks[w][w64];
    unsigned long long below =
        word & ((lane == 63) ? ~0ull : ((1ull << (lane + 1)) - 1ull));
    int btp = wpre[w][w64] + __popcll(below) - 1;
    btp_out[b * SS + s] = (float)btp;
    if ((word >> lane) & 1ull) pstart[b * SS + btp] = s;
  }
}

// per-patch mean pooling (contiguous ranges), zero-fill padding patches
__global__ void patch_kernel(const float* __restrict__ bemb, const int* __restrict__ pstart,
                             const int* __restrict__ npatch, float* __restrict__ pe_out,
                             float* __restrict__ plen_out) {
  int bp = blockIdx.x;
  int b = bp >> 11;
  int p = bp & (SS - 1);
  int c = threadIdx.x;
  int np = npatch[b];
  size_t outidx = (size_t)bp * DM + c;
  if (p >= np) {
    pe_out[outidx] = 0.f;
    if (c == 0) plen_out[bp] = 0.f;
    return;
  }
  int start = pstart[b * SS + p];
  int end = (p + 1 < np) ? pstart[b * SS + p + 1] : SS;
  float acc = 0.f;
  for (int t = start; t < end; ++t) acc += bemb[((size_t)b * SS + t) * DM + c];
  pe_out[outidx] = acc * frcp((float)(end - start));
  if (c == 0) plen_out[bp] = (float)(end - start);
}

// ---------------------------------------------------------------------------
// Launcher — 8 dispatches total
// ---------------------------------------------------------------------------
extern "C" void kernel_launch(void* const* d_in, const int* in_sizes, int n_in,
                              void* d_out, int out_size, void* d_ws, size_t ws_size,
                              hipStream_t stream) {
  const int* bytes = (const int*)d_in[0];
  const float* bemb = (const float*)d_in[1];
  const float* embed_w = (const float*)d_in[2];
  const float* in_proj_w = (const float*)d_in[3];
  const float* conv_w = (const float*)d_in[4];
  const float* conv_b = (const float*)d_in[5];
  const float* x_proj_w = (const float*)d_in[6];
  const float* dt_w = (const float*)d_in[7];
  const float* dt_b = (const float*)d_in[8];
  const float* A_log = (const float*)d_in[9];
  const float* D_param = (const float*)d_in[10];
  const float* out_w = (const float*)d_in[11];
  const float* norm_w = (const float*)d_in[12];
  const float* head_w = (const float*)d_in[13];

  float* out = (float*)d_out;
  float* pe_out = out;                      // (B,S,DM)
  float* plen_out = out + (size_t)TT * DM;  // (B,S)
  float* btp_out = plen_out + TT;           // (B,S)

  char* wsb = (char*)d_ws;
  size_t off = 0;
  auto alloc = [&](size_t bytes_) -> void* {
    void* p = wsb + off;
    off += (bytes_ + 255) & ~(size_t)255;
    return p;
  };
  float* A2 = (float*)alloc((size_t)NLAYERS * DI * DSTATE * 4);
  __hip_bfloat16* xb = (__hip_bfloat16*)alloc((size_t)TT * DM * 2);
  __hip_bfloat16* xz = (__hip_bfloat16*)alloc((size_t)TT * 2 * DI * 2);
  float* ent = (float*)alloc((size_t)TT * 4);
  int* pstart = (int*)alloc((size_t)TT * 4);
  int* npatch = (int*)alloc(256);
  __hip_bfloat16* inWt = (__hip_bfloat16*)alloc((size_t)NLAYERS * 2 * DI * DM * 2);
  __hip_bfloat16* dtWt = (__hip_bfloat16*)alloc((size_t)NLAYERS * DI * DI * 2);
  __hip_bfloat16* oWt = (__hip_bfloat16*)alloc((size_t)NLAYERS * DM * DI * 2);
  __hip_bfloat16* xpWt = (__hip_bfloat16*)alloc((size_t)NLAYERS * 32 * DI * 2);
  __hip_bfloat16* headWt = (__hip_bfloat16*)alloc((size_t)VOCAB * DM * 2);

  // 1: weight prep (tiled transpose) + A2 + embedding
  prep_kernel<<<T_ALL, 256, 0, stream>>>(
      A_log, A2, head_w, headWt, in_proj_w, inWt, dt_w, dtWt, out_w, oWt,
      x_proj_w, xpWt, bytes, embed_w, xb);

  // 2..5: two Mamba layers, 2 dispatches each
  for (int l = 0; l < NLAYERS; ++l) {
    gemm_mfma<<<dim3(2 * DI / 128, TT / 128), 256, 0, stream>>>(
        (const __bf16*)xb, (const __bf16*)(inWt + (size_t)l * 2 * DI * DM),
        (__hip_bfloat16*)xz, TT, 2 * DI, DM);
    mamba_fused<<<TT / TW, 256, 0, stream>>>(
        xz, (const __bf16*)(dtWt + (size_t)l * DI * DI),
        (const __bf16*)(oWt + (size_t)l * DM * DI),
        (const __bf16*)(xpWt + (size_t)l * 32 * DI),
        conv_w + (size_t)l * DI * DCONV, conv_b + (size_t)l * DI,
        A2 + (size_t)l * DI * DSTATE, dt_b + (size_t)l * DI,
        D_param + (size_t)l * DI, norm_w + (size_t)l * DM, xb);
  }

  // 6: head + entropy
  head_entropy<<<TT / 64, 256, 0, stream>>>(xb, (const __bf16*)headWt, ent);

  // 7: boundary scan
  scan_kernel<<<1, 512, 0, stream>>>(ent, btp_out, pstart, npatch);

  // 8: patch mean pooling
  patch_kernel<<<TT, DM, 0, stream>>>(bemb, pstart, npatch, pe_out, plen_out);
}